// Round 1
// baseline (1505.073 us; speedup 1.0000x reference)
//
#include <hip/hip_runtime.h>

#define NG 256
#define NG2 (NG*NG)

constexpr float DX      = 1.0f / 256.0f;
constexpr float INV_DX  = 256.0f;
constexpr float DT      = 2e-5f;
constexpr float P_VOL   = (1.0f/512.0f) * (1.0f/512.0f);
constexpr float P_MASS  = P_VOL;           // rho = 1
constexpr float MU_0    = 1000.0f / (2.0f * 1.2f);            // E/(2(1+nu))
constexpr float LAM_0   = 1000.0f * 0.2f / (1.2f * 0.6f);     // E nu/((1+nu)(1-2nu))
constexpr float GRAV    = 50.0f;

__global__ __launch_bounds__(256) void p2g_kernel(
    const float* __restrict__ x, const float* __restrict__ v,
    const float* __restrict__ C, const float* __restrict__ F,
    const int* __restrict__ mat, const float* __restrict__ Jp,
    float* __restrict__ gm, float* __restrict__ gvx, float* __restrict__ gvy,
    float* __restrict__ F_out, float* __restrict__ mat_out, float* __restrict__ Jp_out,
    int n)
{
    int i = blockIdx.x * blockDim.x + threadIdx.x;
    if (i >= n) return;

    float px = x[2*i],   py = x[2*i+1];
    float vx = v[2*i],   vy = v[2*i+1];
    float C00 = C[4*i],  C01 = C[4*i+1], C10 = C[4*i+2], C11 = C[4*i+3];
    float a = F[4*i], b = F[4*i+1], c = F[4*i+2], d = F[4*i+3];
    int   m  = mat[i];
    float jp = Jp[i];

    float bxf = floorf(px * INV_DX - 0.5f), byf = floorf(py * INV_DX - 0.5f);
    float fx = px * INV_DX - bxf, fy = py * INV_DX - byf;
    float wxs[3] = { 0.5f*(1.5f-fx)*(1.5f-fx), 0.75f-(fx-1.0f)*(fx-1.0f), 0.5f*(fx-0.5f)*(fx-0.5f) };
    float wys[3] = { 0.5f*(1.5f-fy)*(1.5f-fy), 0.75f-(fy-1.0f)*(fy-1.0f), 0.5f*(fy-0.5f)*(fy-0.5f) };

    // F += dt * C @ F
    float na = a + DT*(C00*a + C01*c);
    float nb = b + DT*(C00*b + C01*d);
    float nc = c + DT*(C10*a + C11*c);
    float nd = d + DT*(C10*b + C11*d);
    a = na; b = nb; c = nc; d = nd;

    float h = __expf(10.0f * (1.0f - jp));
    h = expf(10.0f * (1.0f - jp));   // use precise expf for fidelity
    if (m == 1) h = 0.3f;
    float mu  = (m == 0) ? 0.0f : MU_0 * h;
    float lam = LAM_0 * h;

    // ---- closed-form 2x2 SVD via eigendecomposition of A^T A ----
    float S00 = a*a + c*c, S01 = a*b + c*d, S11 = b*b + d*d;
    float mh = 0.5f*(S00 + S11), dh = 0.5f*(S00 - S11);
    float delta = sqrtf(dh*dh + S01*S01);
    float sig1 = sqrtf(fmaxf(mh + delta, 0.0f));
    float sig2 = sqrtf(fmaxf(mh - delta, 0.0f));
    // eigenvector of the larger eigenvalue (well-conditioned branch)
    float e0, e1;
    if (dh >= 0.0f) { e0 = delta + dh; e1 = S01; }
    else            { e0 = S01;        e1 = delta - dh; }
    float elen = sqrtf(e0*e0 + e1*e1);
    float vc, vs;
    if (elen > 1e-30f) { float il = 1.0f/elen; vc = e0*il; vs = e1*il; }
    else               { vc = 1.0f; vs = 0.0f; }
    float inv1 = 1.0f / fmaxf(sig1, 1e-30f);
    float inv2 = 1.0f / fmaxf(sig2, 1e-30f);
    float u1x = ( a*vc + b*vs) * inv1, u1y = ( c*vc + d*vs) * inv1;
    float u2x = (-a*vs + b*vc) * inv2, u2y = (-c*vs + d*vc) * inv2;

    // snow plasticity
    if (m == 2) {
        float c1 = fminf(fmaxf(sig1, 1.0f - 2.5e-2f), 1.0f + 4.5e-3f);
        float c2 = fminf(fmaxf(sig2, 1.0f - 2.5e-2f), 1.0f + 4.5e-3f);
        jp = jp * (sig1 / c1) * (sig2 / c2);
        sig1 = c1; sig2 = c2;
    }
    float J = sig1 * sig2;

    if (m == 0) {              // fluid: F = sqrt(J) I
        float s = sqrtf(J);
        a = s; b = 0.0f; c = 0.0f; d = s;
    } else if (m == 2) {       // snow: F = U diag(sig) Vh
        a = sig1*u1x*vc - sig2*u2x*vs;
        b = sig1*u1x*vs + sig2*u2x*vc;
        c = sig1*u1y*vc - sig2*u2y*vs;
        d = sig1*u1y*vs + sig2*u2y*vc;
    }
    // R = U Vh
    float R00 = u1x*vc - u2x*vs, R01 = u1x*vs + u2x*vc;
    float R10 = u1y*vc - u2y*vs, R11 = u1y*vs + u2y*vc;

    // stress = 2 mu (F - R) F^T + lam J (J-1) I ; scaled by -dt*P_VOL*4*inv_dx^2 (== -dt)
    float k2mu = 2.0f * mu;
    float fr00 = a - R00, fr01 = b - R01, fr10 = c - R10, fr11 = d - R11;
    float ljj  = lam * J * (J - 1.0f);
    float st00 = k2mu*(fr00*a + fr01*b) + ljj;
    float st01 = k2mu*(fr00*c + fr01*d);
    float st10 = k2mu*(fr10*a + fr11*b);
    float st11 = k2mu*(fr10*c + fr11*d) + ljj;
    const float coef = -DT * P_VOL * 4.0f * INV_DX * INV_DX;
    float A00 = coef*st00 + P_MASS*C00;
    float A01 = coef*st01 + P_MASS*C01;
    float A10 = coef*st10 + P_MASS*C10;
    float A11 = coef*st11 + P_MASS*C11;

    float mvx = P_MASS * vx, mvy = P_MASS * vy;
    int bix = (int)bxf, biy = (int)byf;
    #pragma unroll
    for (int ii = 0; ii < 3; ++ii) {
        float dpx = (bxf + (float)ii) * DX - px;
        int rowbase = (bix + ii) * NG + biy;
        #pragma unroll
        for (int jj = 0; jj < 3; ++jj) {
            float w = wxs[ii] * wys[jj];
            float dpy = (byf + (float)jj) * DX - py;
            int gidx = rowbase + jj;
            atomicAdd(&gvx[gidx], w * (mvx + A00*dpx + A01*dpy));
            atomicAdd(&gvy[gidx], w * (mvy + A10*dpx + A11*dpy));
            atomicAdd(&gm[gidx],  w * P_MASS);
        }
    }

    F_out[4*i] = a; F_out[4*i+1] = b; F_out[4*i+2] = c; F_out[4*i+3] = d;
    mat_out[i] = (float)m;
    Jp_out[i]  = jp;
}

__global__ __launch_bounds__(256) void grid_kernel(
    float* __restrict__ gm, float* __restrict__ gvx, float* __restrict__ gvy)
{
    int idx = blockIdx.x * blockDim.x + threadIdx.x;
    if (idx >= NG2) return;
    int i = idx >> 8, j = idx & (NG - 1);
    float mass = gm[idx];
    float vx = gvx[idx], vy = gvy[idx];
    if (mass > 0.0f) {
        float im = 1.0f / fmaxf(mass, 1e-12f);
        vx *= im; vy *= im;
    }
    vy -= DT * GRAV;
    if (i < 3)      vx = fmaxf(vx, 0.0f);
    if (i >= NG-2)  vx = fminf(vx, 0.0f);
    if (j < 3)      vy = fmaxf(vy, 0.0f);
    if (j >= NG-2)  vy = fminf(vy, 0.0f);
    gvx[idx] = vx; gvy[idx] = vy;
}

__global__ __launch_bounds__(256) void g2p_kernel(
    const float* __restrict__ x,
    const float* __restrict__ gvx, const float* __restrict__ gvy,
    float* __restrict__ x_out, float* __restrict__ v_out, float* __restrict__ C_out,
    int n)
{
    int i = blockIdx.x * blockDim.x + threadIdx.x;
    if (i >= n) return;

    float px = x[2*i], py = x[2*i+1];
    float bxf = floorf(px * INV_DX - 0.5f), byf = floorf(py * INV_DX - 0.5f);
    float fx = px * INV_DX - bxf, fy = py * INV_DX - byf;
    float wxs[3] = { 0.5f*(1.5f-fx)*(1.5f-fx), 0.75f-(fx-1.0f)*(fx-1.0f), 0.5f*(fx-0.5f)*(fx-0.5f) };
    float wys[3] = { 0.5f*(1.5f-fy)*(1.5f-fy), 0.75f-(fy-1.0f)*(fy-1.0f), 0.5f*(fy-0.5f)*(fy-0.5f) };
    int bix = (int)bxf, biy = (int)byf;

    float nvx = 0.0f, nvy = 0.0f;
    float c00 = 0.0f, c01 = 0.0f, c10 = 0.0f, c11 = 0.0f;
    #pragma unroll
    for (int ii = 0; ii < 3; ++ii) {
        float posx = (bxf + (float)ii) * DX;
        int rowbase = (bix + ii) * NG + biy;
        #pragma unroll
        for (int jj = 0; jj < 3; ++jj) {
            float w = wxs[ii] * wys[jj];
            float posy = (byf + (float)jj) * DX;
            float gx = gvx[rowbase + jj], gy = gvy[rowbase + jj];
            nvx += w * gx; nvy += w * gy;
            c00 += w * gx * posx; c01 += w * gx * posy;
            c10 += w * gy * posx; c11 += w * gy * posy;
        }
    }
    const float K = 4.0f * INV_DX * INV_DX;
    c00 = (c00 - nvx * px) * K; c01 = (c01 - nvx * py) * K;
    c10 = (c10 - nvy * px) * K; c11 = (c11 - nvy * py) * K;

    x_out[2*i]   = px + DT * nvx;
    x_out[2*i+1] = py + DT * nvy;
    v_out[2*i]   = nvx; v_out[2*i+1] = nvy;
    C_out[4*i]   = c00; C_out[4*i+1] = c01;
    C_out[4*i+2] = c10; C_out[4*i+3] = c11;
}

extern "C" void kernel_launch(void* const* d_in, const int* in_sizes, int n_in,
                              void* d_out, int out_size, void* d_ws, size_t ws_size,
                              hipStream_t stream) {
    const float* x   = (const float*)d_in[0];
    const float* v   = (const float*)d_in[1];
    const float* C   = (const float*)d_in[2];
    const float* F   = (const float*)d_in[3];
    const int*   mat = (const int*)d_in[4];
    const float* Jp  = (const float*)d_in[5];

    int n = in_sizes[0] / 2;

    float* out     = (float*)d_out;
    float* x_out   = out;
    float* v_out   = out + (size_t)2*n;
    float* C_out   = out + (size_t)4*n;
    float* F_out   = out + (size_t)8*n;
    float* mat_out = out + (size_t)12*n;
    float* Jp_out  = out + (size_t)13*n;

    float* gm  = (float*)d_ws;
    float* gvx = gm  + NG2;
    float* gvy = gvx + NG2;

    hipMemsetAsync(d_ws, 0, (size_t)3 * NG2 * sizeof(float), stream);

    int blocks = (n + 255) / 256;
    p2g_kernel<<<blocks, 256, 0, stream>>>(x, v, C, F, mat, Jp,
                                           gm, gvx, gvy,
                                           F_out, mat_out, Jp_out, n);
    grid_kernel<<<NG2 / 256, 256, 0, stream>>>(gm, gvx, gvy);
    g2p_kernel<<<blocks, 256, 0, stream>>>(x, gvx, gvy, x_out, v_out, C_out, n);
}

// Round 2
// 223.275 us; speedup vs baseline: 6.7409x; 6.7409x over previous
//
#include <hip/hip_runtime.h>

#define NG 256
#define NG2 (NG*NG)

constexpr float DX      = 1.0f / 256.0f;
constexpr float INV_DX  = 256.0f;
constexpr float DT      = 2e-5f;
constexpr float P_VOL   = (1.0f/512.0f) * (1.0f/512.0f);
constexpr float P_MASS  = P_VOL;           // rho = 1
constexpr float MU_0    = 1000.0f / (2.0f * 1.2f);            // E/(2(1+nu))
constexpr float LAM_0   = 1000.0f * 0.2f / (1.2f * 0.6f);     // E nu/((1+nu)(1-2nu))
constexpr float GRAV    = 50.0f;

__device__ __forceinline__ int bin_of(float px, float py) {
    int bx = (int)floorf(px * INV_DX - 0.5f);
    int by = (int)floorf(py * INV_DX - 0.5f);
    bx = min(max(bx, 0), NG - 1);
    by = min(max(by, 0), NG - 1);
    return (bx << 8) | by;
}

// quadratic B-spline weight as a function of (node - particle) distance in cells
__device__ __forceinline__ float bw(float t) {
    float at = fabsf(t);
    float a  = fmaxf(1.5f - at, 0.0f);
    float w1 = 0.75f - t * t;
    float w2 = 0.5f * a * a;
    return (at < 0.5f) ? w1 : w2;
}

// ---------------- sorted-gather path ----------------

__global__ __launch_bounds__(256) void binrank_kernel(
    const float* __restrict__ x, int* __restrict__ counts, int* __restrict__ rank, int n)
{
    int i = blockIdx.x * blockDim.x + threadIdx.x;
    if (i >= n) return;
    float2 p = ((const float2*)x)[i];
    int b = bin_of(p.x, p.y);
    rank[i] = atomicAdd(&counts[b], 1);
}

__global__ __launch_bounds__(256) void scan1_kernel(
    const int* __restrict__ counts, int* __restrict__ starts, int* __restrict__ bsum)
{
    __shared__ int tmp[256];
    int t = threadIdx.x, b = blockIdx.x;
    int v = counts[b * 256 + t];
    tmp[t] = v;
    __syncthreads();
    #pragma unroll
    for (int off = 1; off < 256; off <<= 1) {
        int add = (t >= off) ? tmp[t - off] : 0;
        __syncthreads();
        tmp[t] += add;
        __syncthreads();
    }
    starts[b * 256 + t] = tmp[t] - v;          // exclusive within block
    if (t == 255) bsum[b] = tmp[255];          // block total
}

__global__ __launch_bounds__(256) void scan2_kernel(int* __restrict__ bsum)
{
    __shared__ int tmp[256];
    int t = threadIdx.x;
    int v = bsum[t];
    tmp[t] = v;
    __syncthreads();
    #pragma unroll
    for (int off = 1; off < 256; off <<= 1) {
        int add = (t >= off) ? tmp[t - off] : 0;
        __syncthreads();
        tmp[t] += add;
        __syncthreads();
    }
    bsum[t] = tmp[t] - v;                      // exclusive
}

__global__ __launch_bounds__(256) void scan3_kernel(
    int* __restrict__ starts, const int* __restrict__ bsum, int n)
{
    int i = blockIdx.x * blockDim.x + threadIdx.x;
    if (i < NG2) starts[i] += bsum[i >> 8];
    if (i == 0) starts[NG2] = n;
}

__global__ __launch_bounds__(256) void compute_scatter_kernel(
    const float* __restrict__ x, const float* __restrict__ v,
    const float* __restrict__ C, const float* __restrict__ F,
    const int* __restrict__ mat, const float* __restrict__ Jp,
    const int* __restrict__ starts, const int* __restrict__ rank,
    float* __restrict__ srec,
    float* __restrict__ F_out, float* __restrict__ mat_out, float* __restrict__ Jp_out,
    int n)
{
    int i = blockIdx.x * blockDim.x + threadIdx.x;
    if (i >= n) return;

    float px = x[2*i],   py = x[2*i+1];
    float vx = v[2*i],   vy = v[2*i+1];
    float C00 = C[4*i],  C01 = C[4*i+1], C10 = C[4*i+2], C11 = C[4*i+3];
    float a = F[4*i], b = F[4*i+1], c = F[4*i+2], d = F[4*i+3];
    int   m  = mat[i];
    float jp = Jp[i];

    // F += dt * C @ F
    float na = a + DT*(C00*a + C01*c);
    float nb = b + DT*(C00*b + C01*d);
    float nc = c + DT*(C10*a + C11*c);
    float nd = d + DT*(C10*b + C11*d);
    a = na; b = nb; c = nc; d = nd;

    float h = expf(10.0f * (1.0f - jp));
    if (m == 1) h = 0.3f;
    float mu  = (m == 0) ? 0.0f : MU_0 * h;
    float lam = LAM_0 * h;

    // closed-form 2x2 SVD via eigendecomposition of A^T A
    float S00 = a*a + c*c, S01 = a*b + c*d, S11 = b*b + d*d;
    float mh = 0.5f*(S00 + S11), dh = 0.5f*(S00 - S11);
    float delta = sqrtf(dh*dh + S01*S01);
    float sig1 = sqrtf(fmaxf(mh + delta, 0.0f));
    float sig2 = sqrtf(fmaxf(mh - delta, 0.0f));
    float e0, e1;
    if (dh >= 0.0f) { e0 = delta + dh; e1 = S01; }
    else            { e0 = S01;        e1 = delta - dh; }
    float elen = sqrtf(e0*e0 + e1*e1);
    float vc, vs;
    if (elen > 1e-30f) { float il = 1.0f/elen; vc = e0*il; vs = e1*il; }
    else               { vc = 1.0f; vs = 0.0f; }
    float inv1 = 1.0f / fmaxf(sig1, 1e-30f);
    float inv2 = 1.0f / fmaxf(sig2, 1e-30f);
    float u1x = ( a*vc + b*vs) * inv1, u1y = ( c*vc + d*vs) * inv1;
    float u2x = (-a*vs + b*vc) * inv2, u2y = (-c*vs + d*vc) * inv2;

    if (m == 2) {   // snow plasticity
        float c1 = fminf(fmaxf(sig1, 1.0f - 2.5e-2f), 1.0f + 4.5e-3f);
        float c2 = fminf(fmaxf(sig2, 1.0f - 2.5e-2f), 1.0f + 4.5e-3f);
        jp = jp * (sig1 / c1) * (sig2 / c2);
        sig1 = c1; sig2 = c2;
    }
    float J = sig1 * sig2;

    if (m == 0) {              // fluid: F = sqrt(J) I
        float s = sqrtf(J);
        a = s; b = 0.0f; c = 0.0f; d = s;
    } else if (m == 2) {       // snow: F = U diag(sig) Vh
        a = sig1*u1x*vc - sig2*u2x*vs;
        b = sig1*u1x*vs + sig2*u2x*vc;
        c = sig1*u1y*vc - sig2*u2y*vs;
        d = sig1*u1y*vs + sig2*u2y*vc;
    }
    float R00 = u1x*vc - u2x*vs, R01 = u1x*vs + u2x*vc;
    float R10 = u1y*vc - u2y*vs, R11 = u1y*vs + u2y*vc;

    float k2mu = 2.0f * mu;
    float fr00 = a - R00, fr01 = b - R01, fr10 = c - R10, fr11 = d - R11;
    float ljj  = lam * J * (J - 1.0f);
    float st00 = k2mu*(fr00*a + fr01*b) + ljj;
    float st01 = k2mu*(fr00*c + fr01*d);
    float st10 = k2mu*(fr10*a + fr11*b);
    float st11 = k2mu*(fr10*c + fr11*d) + ljj;
    const float coef = -DT * P_VOL * 4.0f * INV_DX * INV_DX;
    float A00 = coef*st00 + P_MASS*C00;
    float A01 = coef*st01 + P_MASS*C01;
    float A10 = coef*st10 + P_MASS*C10;
    float A11 = coef*st11 + P_MASS*C11;

    // record: {px, py, bx_, by_} {A00, A01, A10, A11}, bx_ = P_MASS*v - A*x
    float bx_ = P_MASS*vx - (A00*px + A01*py);
    float by_ = P_MASS*vy - (A10*px + A11*py);

    int bidx = bin_of(px, py);
    int sidx = starts[bidx] + rank[i];
    float4* s4 = (float4*)srec;
    s4[2*sidx]     = make_float4(px, py, bx_, by_);
    s4[2*sidx + 1] = make_float4(A00, A01, A10, A11);

    F_out[4*i] = a; F_out[4*i+1] = b; F_out[4*i+2] = c; F_out[4*i+3] = d;
    mat_out[i] = (float)m;
    Jp_out[i]  = jp;
}

// one thread per grid cell: gather from 3 contiguous sorted ranges, fuse grid ops
__global__ __launch_bounds__(256) void gather_grid_kernel(
    const float* __restrict__ srec, const int* __restrict__ starts,
    float2* __restrict__ gv)
{
    int gi = blockIdx.x;        // row
    int gj = threadIdx.x;       // col
    int idx = (gi << 8) | gj;

    float posx = (float)gi * DX, posy = (float)gj * DX;
    float fgi = (float)gi, fgj = (float)gj;
    float msum = 0.0f, mvx = 0.0f, mvy = 0.0f;

    int i0 = max(gi - 2, 0);
    int j0 = max(gj - 2, 0);
    const float4* s4 = (const float4*)srec;

    for (int bi = i0; bi <= gi; ++bi) {
        int row = bi << 8;
        int s = starts[row + j0];
        int e = starts[row + gj + 1];   // row+gj+1 <= row+256 -> next row start (valid, starts[NG2]=n)
        for (int k = s; k < e; ++k) {
            float4 r0 = s4[2*k];
            float4 r1 = s4[2*k + 1];
            float wx = bw(r0.x * INV_DX - fgi);
            float wy = bw(r0.y * INV_DX - fgj);
            float w = wx * wy;
            msum += w;
            mvx += w * (r0.z + r1.x * posx + r1.y * posy);
            mvy += w * (r0.w + r1.z * posx + r1.w * posy);
        }
    }

    float mass = msum * P_MASS;
    float vx = mvx, vy = mvy;
    if (mass > 0.0f) {
        float im = 1.0f / fmaxf(mass, 1e-12f);
        vx *= im; vy *= im;
    }
    vy -= DT * GRAV;
    if (gi < 3)      vx = fmaxf(vx, 0.0f);
    if (gi >= NG-2)  vx = fminf(vx, 0.0f);
    if (gj < 3)      vy = fmaxf(vy, 0.0f);
    if (gj >= NG-2)  vy = fminf(vy, 0.0f);
    gv[idx] = make_float2(vx, vy);
}

__global__ __launch_bounds__(256) void g2p_kernel(
    const float* __restrict__ x, const float2* __restrict__ gv,
    float* __restrict__ x_out, float* __restrict__ v_out, float* __restrict__ C_out,
    int n)
{
    int i = blockIdx.x * blockDim.x + threadIdx.x;
    if (i >= n) return;

    float px = x[2*i], py = x[2*i+1];
    float bxf = floorf(px * INV_DX - 0.5f), byf = floorf(py * INV_DX - 0.5f);
    float fx = px * INV_DX - bxf, fy = py * INV_DX - byf;
    float wxs[3] = { 0.5f*(1.5f-fx)*(1.5f-fx), 0.75f-(fx-1.0f)*(fx-1.0f), 0.5f*(fx-0.5f)*(fx-0.5f) };
    float wys[3] = { 0.5f*(1.5f-fy)*(1.5f-fy), 0.75f-(fy-1.0f)*(fy-1.0f), 0.5f*(fy-0.5f)*(fy-0.5f) };
    int bix = (int)bxf, biy = (int)byf;

    float nvx = 0.0f, nvy = 0.0f;
    float c00 = 0.0f, c01 = 0.0f, c10 = 0.0f, c11 = 0.0f;
    #pragma unroll
    for (int ii = 0; ii < 3; ++ii) {
        float posx = (bxf + (float)ii) * DX;
        int rowbase = (bix + ii) * NG + biy;
        #pragma unroll
        for (int jj = 0; jj < 3; ++jj) {
            float w = wxs[ii] * wys[jj];
            float posy = (byf + (float)jj) * DX;
            float2 g = gv[rowbase + jj];
            nvx += w * g.x; nvy += w * g.y;
            c00 += w * g.x * posx; c01 += w * g.x * posy;
            c10 += w * g.y * posx; c11 += w * g.y * posy;
        }
    }
    const float K = 4.0f * INV_DX * INV_DX;
    c00 = (c00 - nvx * px) * K; c01 = (c01 - nvx * py) * K;
    c10 = (c10 - nvy * px) * K; c11 = (c11 - nvy * py) * K;

    x_out[2*i]   = px + DT * nvx;
    x_out[2*i+1] = py + DT * nvy;
    v_out[2*i]   = nvx; v_out[2*i+1] = nvy;
    C_out[4*i]   = c00; C_out[4*i+1] = c01;
    C_out[4*i+2] = c10; C_out[4*i+3] = c11;
}

// ---------------- fallback (R1 atomic path) ----------------

__global__ __launch_bounds__(256) void p2g_atomic_kernel(
    const float* __restrict__ x, const float* __restrict__ v,
    const float* __restrict__ C, const float* __restrict__ F,
    const int* __restrict__ mat, const float* __restrict__ Jp,
    float* __restrict__ gm, float2* __restrict__ gv,
    float* __restrict__ F_out, float* __restrict__ mat_out, float* __restrict__ Jp_out,
    int n)
{
    int i = blockIdx.x * blockDim.x + threadIdx.x;
    if (i >= n) return;
    float px = x[2*i],   py = x[2*i+1];
    float vx = v[2*i],   vy = v[2*i+1];
    float C00 = C[4*i],  C01 = C[4*i+1], C10 = C[4*i+2], C11 = C[4*i+3];
    float a = F[4*i], b = F[4*i+1], c = F[4*i+2], d = F[4*i+3];
    int   m  = mat[i];
    float jp = Jp[i];

    float bxf = floorf(px * INV_DX - 0.5f), byf = floorf(py * INV_DX - 0.5f);
    float fx = px * INV_DX - bxf, fy = py * INV_DX - byf;
    float wxs[3] = { 0.5f*(1.5f-fx)*(1.5f-fx), 0.75f-(fx-1.0f)*(fx-1.0f), 0.5f*(fx-0.5f)*(fx-0.5f) };
    float wys[3] = { 0.5f*(1.5f-fy)*(1.5f-fy), 0.75f-(fy-1.0f)*(fy-1.0f), 0.5f*(fy-0.5f)*(fy-0.5f) };

    float na = a + DT*(C00*a + C01*c);
    float nb = b + DT*(C00*b + C01*d);
    float nc = c + DT*(C10*a + C11*c);
    float nd = d + DT*(C10*b + C11*d);
    a = na; b = nb; c = nc; d = nd;

    float h = expf(10.0f * (1.0f - jp));
    if (m == 1) h = 0.3f;
    float mu  = (m == 0) ? 0.0f : MU_0 * h;
    float lam = LAM_0 * h;

    float S00 = a*a + c*c, S01 = a*b + c*d, S11 = b*b + d*d;
    float mh = 0.5f*(S00 + S11), dh = 0.5f*(S00 - S11);
    float delta = sqrtf(dh*dh + S01*S01);
    float sig1 = sqrtf(fmaxf(mh + delta, 0.0f));
    float sig2 = sqrtf(fmaxf(mh - delta, 0.0f));
    float e0, e1;
    if (dh >= 0.0f) { e0 = delta + dh; e1 = S01; }
    else            { e0 = S01;        e1 = delta - dh; }
    float elen = sqrtf(e0*e0 + e1*e1);
    float vc, vs;
    if (elen > 1e-30f) { float il = 1.0f/elen; vc = e0*il; vs = e1*il; }
    else               { vc = 1.0f; vs = 0.0f; }
    float inv1 = 1.0f / fmaxf(sig1, 1e-30f);
    float inv2 = 1.0f / fmaxf(sig2, 1e-30f);
    float u1x = ( a*vc + b*vs) * inv1, u1y = ( c*vc + d*vs) * inv1;
    float u2x = (-a*vs + b*vc) * inv2, u2y = (-c*vs + d*vc) * inv2;

    if (m == 2) {
        float c1 = fminf(fmaxf(sig1, 1.0f - 2.5e-2f), 1.0f + 4.5e-3f);
        float c2 = fminf(fmaxf(sig2, 1.0f - 2.5e-2f), 1.0f + 4.5e-3f);
        jp = jp * (sig1 / c1) * (sig2 / c2);
        sig1 = c1; sig2 = c2;
    }
    float J = sig1 * sig2;
    if (m == 0) { float s = sqrtf(J); a = s; b = 0.0f; c = 0.0f; d = s; }
    else if (m == 2) {
        a = sig1*u1x*vc - sig2*u2x*vs;
        b = sig1*u1x*vs + sig2*u2x*vc;
        c = sig1*u1y*vc - sig2*u2y*vs;
        d = sig1*u1y*vs + sig2*u2y*vc;
    }
    float R00 = u1x*vc - u2x*vs, R01 = u1x*vs + u2x*vc;
    float R10 = u1y*vc - u2y*vs, R11 = u1y*vs + u2y*vc;

    float k2mu = 2.0f * mu;
    float fr00 = a - R00, fr01 = b - R01, fr10 = c - R10, fr11 = d - R11;
    float ljj  = lam * J * (J - 1.0f);
    float st00 = k2mu*(fr00*a + fr01*b) + ljj;
    float st01 = k2mu*(fr00*c + fr01*d);
    float st10 = k2mu*(fr10*a + fr11*b);
    float st11 = k2mu*(fr10*c + fr11*d) + ljj;
    const float coef = -DT * P_VOL * 4.0f * INV_DX * INV_DX;
    float A00 = coef*st00 + P_MASS*C00;
    float A01 = coef*st01 + P_MASS*C01;
    float A10 = coef*st10 + P_MASS*C10;
    float A11 = coef*st11 + P_MASS*C11;

    float mvx = P_MASS * vx, mvy = P_MASS * vy;
    int bix = (int)bxf, biy = (int)byf;
    #pragma unroll
    for (int ii = 0; ii < 3; ++ii) {
        float dpx = (bxf + (float)ii) * DX - px;
        int rowbase = (bix + ii) * NG + biy;
        #pragma unroll
        for (int jj = 0; jj < 3; ++jj) {
            float w = wxs[ii] * wys[jj];
            float dpy = (byf + (float)jj) * DX - py;
            int gidx = rowbase + jj;
            atomicAdd(&gv[gidx].x, w * (mvx + A00*dpx + A01*dpy));
            atomicAdd(&gv[gidx].y, w * (mvy + A10*dpx + A11*dpy));
            atomicAdd(&gm[gidx],  w * P_MASS);
        }
    }
    F_out[4*i] = a; F_out[4*i+1] = b; F_out[4*i+2] = c; F_out[4*i+3] = d;
    mat_out[i] = (float)m;
    Jp_out[i]  = jp;
}

__global__ __launch_bounds__(256) void grid_fallback_kernel(
    const float* __restrict__ gm, float2* __restrict__ gv)
{
    int idx = blockIdx.x * blockDim.x + threadIdx.x;
    if (idx >= NG2) return;
    int i = idx >> 8, j = idx & (NG - 1);
    float mass = gm[idx];
    float2 g = gv[idx];
    if (mass > 0.0f) {
        float im = 1.0f / fmaxf(mass, 1e-12f);
        g.x *= im; g.y *= im;
    }
    g.y -= DT * GRAV;
    if (i < 3)      g.x = fmaxf(g.x, 0.0f);
    if (i >= NG-2)  g.x = fminf(g.x, 0.0f);
    if (j < 3)      g.y = fmaxf(g.y, 0.0f);
    if (j >= NG-2)  g.y = fminf(g.y, 0.0f);
    gv[idx] = g;
}

extern "C" void kernel_launch(void* const* d_in, const int* in_sizes, int n_in,
                              void* d_out, int out_size, void* d_ws, size_t ws_size,
                              hipStream_t stream) {
    const float* x   = (const float*)d_in[0];
    const float* v   = (const float*)d_in[1];
    const float* C   = (const float*)d_in[2];
    const float* F   = (const float*)d_in[3];
    const int*   mat = (const int*)d_in[4];
    const float* Jp  = (const float*)d_in[5];

    int n = in_sizes[0] / 2;

    float* out     = (float*)d_out;
    float* x_out   = out;
    float* v_out   = out + (size_t)2*n;
    float* C_out   = out + (size_t)4*n;
    float* F_out   = out + (size_t)8*n;
    float* mat_out = out + (size_t)12*n;
    float* Jp_out  = out + (size_t)13*n;

    int blocks = (n + 255) / 256;

    // workspace layout (sorted-gather path)
    char* ws = (char*)d_ws;
    size_t off = 0;
    int* counts = (int*)(ws + off); off += (size_t)NG2 * 4;
    int* starts = (int*)(ws + off); off += (size_t)(NG2 + 1) * 4;
    int* bsum   = (int*)(ws + off); off += 256 * 4;
    int* rank   = (int*)(ws + off); off += (size_t)n * 4;
    off = (off + 15) & ~(size_t)15;          // 16B align for float4 records
    float* srec = (float*)(ws + off); off += (size_t)n * 8 * 4;
    float2* gv  = (float2*)(ws + off); off += (size_t)NG2 * 8;
    size_t required = off;

    if (ws_size >= required) {
        hipMemsetAsync(counts, 0, (size_t)NG2 * 4, stream);
        binrank_kernel<<<blocks, 256, 0, stream>>>(x, counts, rank, n);
        scan1_kernel<<<NG2/256, 256, 0, stream>>>(counts, starts, bsum);
        scan2_kernel<<<1, 256, 0, stream>>>(bsum);
        scan3_kernel<<<NG2/256, 256, 0, stream>>>(starts, bsum, n);
        compute_scatter_kernel<<<blocks, 256, 0, stream>>>(x, v, C, F, mat, Jp,
                                                           starts, rank, srec,
                                                           F_out, mat_out, Jp_out, n);
        gather_grid_kernel<<<NG, NG, 0, stream>>>(srec, starts, gv);
        g2p_kernel<<<blocks, 256, 0, stream>>>(x, gv, x_out, v_out, C_out, n);
    } else {
        // fallback: atomic scatter path (needs 3*NG2 floats)
        float* gm   = (float*)d_ws;
        float2* gvf = (float2*)(gm + NG2);
        hipMemsetAsync(d_ws, 0, (size_t)3 * NG2 * 4, stream);
        p2g_atomic_kernel<<<blocks, 256, 0, stream>>>(x, v, C, F, mat, Jp,
                                                      gm, gvf, F_out, mat_out, Jp_out, n);
        grid_fallback_kernel<<<NG2/256, 256, 0, stream>>>(gm, gvf);
        g2p_kernel<<<blocks, 256, 0, stream>>>(x, gvf, x_out, v_out, C_out, n);
    }
}

// Round 3
// 171.498 us; speedup vs baseline: 8.7760x; 1.3019x over previous
//
#include <hip/hip_runtime.h>

#define NG 256
#define NG2 (NG*NG)

constexpr float DX      = 1.0f / 256.0f;
constexpr float INV_DX  = 256.0f;
constexpr float DT      = 2e-5f;
constexpr float P_VOL   = (1.0f/512.0f) * (1.0f/512.0f);
constexpr float P_MASS  = P_VOL;           // rho = 1
constexpr float MU_0    = 1000.0f / (2.0f * 1.2f);            // E/(2(1+nu))
constexpr float LAM_0   = 1000.0f * 0.2f / (1.2f * 0.6f);     // E nu/((1+nu)(1-2nu))
constexpr float GRAV    = 50.0f;

__device__ __forceinline__ int bin_of(float px, float py) {
    int bx = (int)floorf(px * INV_DX - 0.5f);
    int by = (int)floorf(py * INV_DX - 0.5f);
    bx = min(max(bx, 0), NG - 1);
    by = min(max(by, 0), NG - 1);
    return (bx << 8) | by;
}

// quadratic B-spline weight as a function of (node - particle) distance in cells
__device__ __forceinline__ float bw(float t) {
    float at = fabsf(t);
    float a  = fmaxf(1.5f - at, 0.0f);
    float w1 = 0.75f - t * t;
    float w2 = 0.5f * a * a;
    return (at < 0.5f) ? w1 : w2;
}

// ---------------- sorted-gather path ----------------

__global__ __launch_bounds__(256) void binrank_kernel(
    const float* __restrict__ x, int* __restrict__ counts, int* __restrict__ rank, int n)
{
    int i = blockIdx.x * blockDim.x + threadIdx.x;
    if (i >= n) return;
    float2 p = ((const float2*)x)[i];
    int b = bin_of(p.x, p.y);
    rank[i] = atomicAdd(&counts[b], 1);
}

__global__ __launch_bounds__(256) void scan1_kernel(
    const int* __restrict__ counts, int* __restrict__ starts, int* __restrict__ bsum)
{
    __shared__ int tmp[256];
    int t = threadIdx.x, b = blockIdx.x;
    int v = counts[b * 256 + t];
    tmp[t] = v;
    __syncthreads();
    #pragma unroll
    for (int off = 1; off < 256; off <<= 1) {
        int add = (t >= off) ? tmp[t - off] : 0;
        __syncthreads();
        tmp[t] += add;
        __syncthreads();
    }
    starts[b * 256 + t] = tmp[t] - v;          // exclusive within block
    if (t == 255) bsum[b] = tmp[255];          // block total
}

__global__ __launch_bounds__(256) void scan2_kernel(int* __restrict__ bsum)
{
    __shared__ int tmp[256];
    int t = threadIdx.x;
    int v = bsum[t];
    tmp[t] = v;
    __syncthreads();
    #pragma unroll
    for (int off = 1; off < 256; off <<= 1) {
        int add = (t >= off) ? tmp[t - off] : 0;
        __syncthreads();
        tmp[t] += add;
        __syncthreads();
    }
    bsum[t] = tmp[t] - v;                      // exclusive
}

__global__ __launch_bounds__(256) void scan3_kernel(
    int* __restrict__ starts, const int* __restrict__ bsum, int n)
{
    int i = blockIdx.x * blockDim.x + threadIdx.x;
    if (i < NG2) starts[i] += bsum[i >> 8];
    if (i == 0) starts[NG2] = n;
}

__global__ __launch_bounds__(256) void compute_scatter_kernel(
    const float* __restrict__ x, const float* __restrict__ v,
    const float* __restrict__ C, const float* __restrict__ F,
    const int* __restrict__ mat, const float* __restrict__ Jp,
    const int* __restrict__ starts, const int* __restrict__ rank,
    float4* __restrict__ srec0, float4* __restrict__ srec1,
    float* __restrict__ F_out, float* __restrict__ mat_out, float* __restrict__ Jp_out,
    int n)
{
    int i = blockIdx.x * blockDim.x + threadIdx.x;
    if (i >= n) return;

    float px = x[2*i],   py = x[2*i+1];
    float vx = v[2*i],   vy = v[2*i+1];
    float C00 = C[4*i],  C01 = C[4*i+1], C10 = C[4*i+2], C11 = C[4*i+3];
    float a = F[4*i], b = F[4*i+1], c = F[4*i+2], d = F[4*i+3];
    int   m  = mat[i];
    float jp = Jp[i];

    // F += dt * C @ F
    float na = a + DT*(C00*a + C01*c);
    float nb = b + DT*(C00*b + C01*d);
    float nc = c + DT*(C10*a + C11*c);
    float nd = d + DT*(C10*b + C11*d);
    a = na; b = nb; c = nc; d = nd;

    float h = expf(10.0f * (1.0f - jp));
    if (m == 1) h = 0.3f;
    float mu  = (m == 0) ? 0.0f : MU_0 * h;
    float lam = LAM_0 * h;

    // closed-form 2x2 SVD via eigendecomposition of A^T A
    float S00 = a*a + c*c, S01 = a*b + c*d, S11 = b*b + d*d;
    float mh = 0.5f*(S00 + S11), dh = 0.5f*(S00 - S11);
    float delta = sqrtf(dh*dh + S01*S01);
    float sig1 = sqrtf(fmaxf(mh + delta, 0.0f));
    float sig2 = sqrtf(fmaxf(mh - delta, 0.0f));
    float e0, e1;
    if (dh >= 0.0f) { e0 = delta + dh; e1 = S01; }
    else            { e0 = S01;        e1 = delta - dh; }
    float elen = sqrtf(e0*e0 + e1*e1);
    float vc, vs;
    if (elen > 1e-30f) { float il = 1.0f/elen; vc = e0*il; vs = e1*il; }
    else               { vc = 1.0f; vs = 0.0f; }
    float inv1 = 1.0f / fmaxf(sig1, 1e-30f);
    float inv2 = 1.0f / fmaxf(sig2, 1e-30f);
    float u1x = ( a*vc + b*vs) * inv1, u1y = ( c*vc + d*vs) * inv1;
    float u2x = (-a*vs + b*vc) * inv2, u2y = (-c*vs + d*vc) * inv2;

    if (m == 2) {   // snow plasticity
        float c1 = fminf(fmaxf(sig1, 1.0f - 2.5e-2f), 1.0f + 4.5e-3f);
        float c2 = fminf(fmaxf(sig2, 1.0f - 2.5e-2f), 1.0f + 4.5e-3f);
        jp = jp * (sig1 / c1) * (sig2 / c2);
        sig1 = c1; sig2 = c2;
    }
    float J = sig1 * sig2;

    if (m == 0) {              // fluid: F = sqrt(J) I
        float s = sqrtf(J);
        a = s; b = 0.0f; c = 0.0f; d = s;
    } else if (m == 2) {       // snow: F = U diag(sig) Vh
        a = sig1*u1x*vc - sig2*u2x*vs;
        b = sig1*u1x*vs + sig2*u2x*vc;
        c = sig1*u1y*vc - sig2*u2y*vs;
        d = sig1*u1y*vs + sig2*u2y*vc;
    }
    float R00 = u1x*vc - u2x*vs, R01 = u1x*vs + u2x*vc;
    float R10 = u1y*vc - u2y*vs, R11 = u1y*vs + u2y*vc;

    float k2mu = 2.0f * mu;
    float fr00 = a - R00, fr01 = b - R01, fr10 = c - R10, fr11 = d - R11;
    float ljj  = lam * J * (J - 1.0f);
    float st00 = k2mu*(fr00*a + fr01*b) + ljj;
    float st01 = k2mu*(fr00*c + fr01*d);
    float st10 = k2mu*(fr10*a + fr11*b);
    float st11 = k2mu*(fr10*c + fr11*d) + ljj;
    const float coef = -DT * P_VOL * 4.0f * INV_DX * INV_DX;
    float A00 = coef*st00 + P_MASS*C00;
    float A01 = coef*st01 + P_MASS*C01;
    float A10 = coef*st10 + P_MASS*C10;
    float A11 = coef*st11 + P_MASS*C11;

    // record: {px, py, bx_, by_} {A00, A01, A10, A11}, bx_ = P_MASS*v - A*x
    float bx_ = P_MASS*vx - (A00*px + A01*py);
    float by_ = P_MASS*vy - (A10*px + A11*py);

    int bidx = bin_of(px, py);
    int sidx = starts[bidx] + rank[i];
    srec0[sidx] = make_float4(px, py, bx_, by_);
    srec1[sidx] = make_float4(A00, A01, A10, A11);

    F_out[4*i] = a; F_out[4*i+1] = b; F_out[4*i+2] = c; F_out[4*i+3] = d;
    mat_out[i] = (float)m;
    Jp_out[i]  = jp;
}

// 4 threads per grid cell: gather from 3 contiguous sorted ranges (strided by
// slice), shuffle-reduce within the 4-lane group, fuse grid ops.
__global__ __launch_bounds__(256) void gather_grid_kernel(
    const float4* __restrict__ srec0, const float4* __restrict__ srec1,
    const int* __restrict__ starts, float2* __restrict__ gv)
{
    int gtid  = blockIdx.x * blockDim.x + threadIdx.x;
    int cell  = gtid >> 2;
    int slice = gtid & 3;
    int gi = cell >> 8, gj = cell & (NG - 1);

    float posx = (float)gi * DX, posy = (float)gj * DX;
    float fgi = (float)gi, fgj = (float)gj;
    float msum = 0.0f, mvx = 0.0f, mvy = 0.0f;

    int i0 = max(gi - 2, 0);
    int j0 = max(gj - 2, 0);

    for (int bi = i0; bi <= gi; ++bi) {
        int row = bi << 8;
        int s = starts[row + j0];
        int e = starts[row + gj + 1];   // end of bin (bi, gj); starts[NG2]=n
        for (int k = s + slice; k < e; k += 4) {
            float4 r0 = srec0[k];
            float4 r1 = srec1[k];
            float w = bw(r0.x * INV_DX - fgi) * bw(r0.y * INV_DX - fgj);
            msum += w;
            mvx += w * (r0.z + r1.x * posx + r1.y * posy);
            mvy += w * (r0.w + r1.z * posx + r1.w * posy);
        }
    }

    // reduce across the 4 slices (lanes differing in bits 0..1 of lane id)
    #pragma unroll
    for (int off = 1; off < 4; off <<= 1) {
        msum += __shfl_xor(msum, off);
        mvx  += __shfl_xor(mvx,  off);
        mvy  += __shfl_xor(mvy,  off);
    }

    if (slice == 0) {
        float mass = msum * P_MASS;
        float vx = mvx, vy = mvy;
        if (mass > 0.0f) {
            float im = 1.0f / fmaxf(mass, 1e-12f);
            vx *= im; vy *= im;
        }
        vy -= DT * GRAV;
        if (gi < 3)      vx = fmaxf(vx, 0.0f);
        if (gi >= NG-2)  vx = fminf(vx, 0.0f);
        if (gj < 3)      vy = fmaxf(vy, 0.0f);
        if (gj >= NG-2)  vy = fminf(vy, 0.0f);
        gv[cell] = make_float2(vx, vy);
    }
}

__global__ __launch_bounds__(256) void g2p_kernel(
    const float* __restrict__ x, const float2* __restrict__ gv,
    float* __restrict__ x_out, float* __restrict__ v_out, float* __restrict__ C_out,
    int n)
{
    int i = blockIdx.x * blockDim.x + threadIdx.x;
    if (i >= n) return;

    float px = x[2*i], py = x[2*i+1];
    float bxf = floorf(px * INV_DX - 0.5f), byf = floorf(py * INV_DX - 0.5f);
    float fx = px * INV_DX - bxf, fy = py * INV_DX - byf;
    float wxs[3] = { 0.5f*(1.5f-fx)*(1.5f-fx), 0.75f-(fx-1.0f)*(fx-1.0f), 0.5f*(fx-0.5f)*(fx-0.5f) };
    float wys[3] = { 0.5f*(1.5f-fy)*(1.5f-fy), 0.75f-(fy-1.0f)*(fy-1.0f), 0.5f*(fy-0.5f)*(fy-0.5f) };
    int bix = (int)bxf, biy = (int)byf;

    float nvx = 0.0f, nvy = 0.0f;
    float c00 = 0.0f, c01 = 0.0f, c10 = 0.0f, c11 = 0.0f;
    #pragma unroll
    for (int ii = 0; ii < 3; ++ii) {
        float posx = (bxf + (float)ii) * DX;
        int rowbase = (bix + ii) * NG + biy;
        #pragma unroll
        for (int jj = 0; jj < 3; ++jj) {
            float w = wxs[ii] * wys[jj];
            float posy = (byf + (float)jj) * DX;
            float2 g = gv[rowbase + jj];
            nvx += w * g.x; nvy += w * g.y;
            c00 += w * g.x * posx; c01 += w * g.x * posy;
            c10 += w * g.y * posx; c11 += w * g.y * posy;
        }
    }
    const float K = 4.0f * INV_DX * INV_DX;
    c00 = (c00 - nvx * px) * K; c01 = (c01 - nvx * py) * K;
    c10 = (c10 - nvy * px) * K; c11 = (c11 - nvy * py) * K;

    x_out[2*i]   = px + DT * nvx;
    x_out[2*i+1] = py + DT * nvy;
    v_out[2*i]   = nvx; v_out[2*i+1] = nvy;
    C_out[4*i]   = c00; C_out[4*i+1] = c01;
    C_out[4*i+2] = c10; C_out[4*i+3] = c11;
}

extern "C" void kernel_launch(void* const* d_in, const int* in_sizes, int n_in,
                              void* d_out, int out_size, void* d_ws, size_t ws_size,
                              hipStream_t stream) {
    const float* x   = (const float*)d_in[0];
    const float* v   = (const float*)d_in[1];
    const float* C   = (const float*)d_in[2];
    const float* F   = (const float*)d_in[3];
    const int*   mat = (const int*)d_in[4];
    const float* Jp  = (const float*)d_in[5];

    int n = in_sizes[0] / 2;

    float* out     = (float*)d_out;
    float* x_out   = out;
    float* v_out   = out + (size_t)2*n;
    float* C_out   = out + (size_t)4*n;
    float* F_out   = out + (size_t)8*n;
    float* mat_out = out + (size_t)12*n;
    float* Jp_out  = out + (size_t)13*n;

    int blocks = (n + 255) / 256;

    // workspace layout (sorted-gather path)
    char* ws = (char*)d_ws;
    size_t off = 0;
    int* counts = (int*)(ws + off); off += (size_t)NG2 * 4;
    int* starts = (int*)(ws + off); off += (size_t)(NG2 + 1) * 4;
    int* bsum   = (int*)(ws + off); off += 256 * 4;
    int* rank   = (int*)(ws + off); off += (size_t)n * 4;
    off = (off + 15) & ~(size_t)15;          // 16B align for float4 records
    float4* srec0 = (float4*)(ws + off); off += (size_t)n * 16;
    float4* srec1 = (float4*)(ws + off); off += (size_t)n * 16;
    float2* gv    = (float2*)(ws + off); off += (size_t)NG2 * 8;
    size_t required = off;

    if (ws_size >= required) {
        hipMemsetAsync(counts, 0, (size_t)NG2 * 4, stream);
        binrank_kernel<<<blocks, 256, 0, stream>>>(x, counts, rank, n);
        scan1_kernel<<<NG2/256, 256, 0, stream>>>(counts, starts, bsum);
        scan2_kernel<<<1, 256, 0, stream>>>(bsum);
        scan3_kernel<<<NG2/256, 256, 0, stream>>>(starts, bsum, n);
        compute_scatter_kernel<<<blocks, 256, 0, stream>>>(x, v, C, F, mat, Jp,
                                                           starts, rank, srec0, srec1,
                                                           F_out, mat_out, Jp_out, n);
        gather_grid_kernel<<<(NG2*4)/256, 256, 0, stream>>>(srec0, srec1, starts, gv);
        g2p_kernel<<<blocks, 256, 0, stream>>>(x, gv, x_out, v_out, C_out, n);
    } else {
        // fallback (should not trigger): recompute with 1 thread/cell using same kernels
        // minimal-footprint path: counts+starts+bsum+rank+gv only is not possible for
        // the gather path, so fall back to nothing-fancy atomic-free reuse is omitted;
        // require the workspace.
        hipMemsetAsync(counts, 0, (size_t)NG2 * 4, stream);
        binrank_kernel<<<blocks, 256, 0, stream>>>(x, counts, rank, n);
        scan1_kernel<<<NG2/256, 256, 0, stream>>>(counts, starts, bsum);
        scan2_kernel<<<1, 256, 0, stream>>>(bsum);
        scan3_kernel<<<NG2/256, 256, 0, stream>>>(starts, bsum, n);
        compute_scatter_kernel<<<blocks, 256, 0, stream>>>(x, v, C, F, mat, Jp,
                                                           starts, rank, srec0, srec1,
                                                           F_out, mat_out, Jp_out, n);
        gather_grid_kernel<<<(NG2*4)/256, 256, 0, stream>>>(srec0, srec1, starts, gv);
        g2p_kernel<<<blocks, 256, 0, stream>>>(x, gv, x_out, v_out, C_out, n);
    }
}

// Round 4
// 147.676 us; speedup vs baseline: 10.1917x; 1.1613x over previous
//
#include <hip/hip_runtime.h>

#define NG 256
#define NG2 (NG*NG)

constexpr float DX      = 1.0f / 256.0f;
constexpr float INV_DX  = 256.0f;
constexpr float DT      = 2e-5f;
constexpr float P_VOL   = (1.0f/512.0f) * (1.0f/512.0f);
constexpr float P_MASS  = P_VOL;           // rho = 1
constexpr float MU_0    = 1000.0f / (2.0f * 1.2f);            // E/(2(1+nu))
constexpr float LAM_0   = 1000.0f * 0.2f / (1.2f * 0.6f);     // E nu/((1+nu)(1-2nu))
constexpr float GRAV    = 50.0f;

__device__ __forceinline__ int bin_of(float px, float py) {
    int bx = (int)floorf(px * INV_DX - 0.5f);
    int by = (int)floorf(py * INV_DX - 0.5f);
    bx = min(max(bx, 0), NG - 1);
    by = min(max(by, 0), NG - 1);
    return (bx << 8) | by;
}

// quadratic B-spline weight as a function of (node - particle) distance in cells
__device__ __forceinline__ float bw(float t) {
    float at = fabsf(t);
    float a  = fmaxf(1.5f - at, 0.0f);
    float w1 = 0.75f - t * t;
    float w2 = 0.5f * a * a;
    return (at < 0.5f) ? w1 : w2;
}

// ---------------- binning + scan ----------------

__global__ __launch_bounds__(256) void binrank_kernel(
    const float* __restrict__ x, int* __restrict__ counts, int* __restrict__ rank, int n)
{
    int i = blockIdx.x * blockDim.x + threadIdx.x;
    if (i >= n) return;
    float2 p = ((const float2*)x)[i];
    int b = bin_of(p.x, p.y);
    rank[i] = atomicAdd(&counts[b], 1);
}

__global__ __launch_bounds__(256) void scan1_kernel(
    const int* __restrict__ counts, int* __restrict__ starts, int* __restrict__ bsum)
{
    __shared__ int tmp[256];
    int t = threadIdx.x, b = blockIdx.x;
    int v = counts[b * 256 + t];
    tmp[t] = v;
    __syncthreads();
    #pragma unroll
    for (int off = 1; off < 256; off <<= 1) {
        int add = (t >= off) ? tmp[t - off] : 0;
        __syncthreads();
        tmp[t] += add;
        __syncthreads();
    }
    starts[b * 256 + t] = tmp[t] - v;          // exclusive within block
    if (t == 255) bsum[b] = tmp[255];          // block total
}

__global__ __launch_bounds__(256) void scan2_kernel(int* __restrict__ bsum)
{
    __shared__ int tmp[256];
    int t = threadIdx.x;
    int v = bsum[t];
    tmp[t] = v;
    __syncthreads();
    #pragma unroll
    for (int off = 1; off < 256; off <<= 1) {
        int add = (t >= off) ? tmp[t - off] : 0;
        __syncthreads();
        tmp[t] += add;
        __syncthreads();
    }
    bsum[t] = tmp[t] - v;                      // exclusive
}

__global__ __launch_bounds__(256) void scan3_kernel(
    int* __restrict__ starts, const int* __restrict__ bsum, int n)
{
    int i = blockIdx.x * blockDim.x + threadIdx.x;
    if (i < NG2) starts[i] += bsum[i >> 8];
    if (i == 0) starts[NG2] = n;
}

// ---------------- particle update + sorted record scatter ----------------

__device__ __forceinline__ void particle_update(
    int i,
    const float2* __restrict__ x2, const float2* __restrict__ v2,
    const float4* __restrict__ C4, const float4* __restrict__ F4,
    const int* __restrict__ mat, const float* __restrict__ Jp,
    const int* __restrict__ starts, const int* __restrict__ rank,
    float4* __restrict__ srec0, float4* __restrict__ srec1,
    float4* __restrict__ F_out4, float* __restrict__ mat_out, float* __restrict__ Jp_out)
{
    float2 xp = x2[i];
    float2 vp = v2[i];
    float4 Cp = C4[i];
    float4 Fp = F4[i];
    int    m  = mat[i];
    float  jp = Jp[i];

    float px = xp.x, py = xp.y;
    float C00 = Cp.x, C01 = Cp.y, C10 = Cp.z, C11 = Cp.w;
    float a = Fp.x, b = Fp.y, c = Fp.z, d = Fp.w;

    // F += dt * C @ F
    float na = a + DT*(C00*a + C01*c);
    float nb = b + DT*(C00*b + C01*d);
    float nc = c + DT*(C10*a + C11*c);
    float nd = d + DT*(C10*b + C11*d);
    a = na; b = nb; c = nc; d = nd;

    float h = expf(10.0f * (1.0f - jp));
    if (m == 1) h = 0.3f;
    float mu  = (m == 0) ? 0.0f : MU_0 * h;
    float lam = LAM_0 * h;

    // closed-form 2x2 SVD via eigendecomposition of A^T A
    float S00 = a*a + c*c, S01 = a*b + c*d, S11 = b*b + d*d;
    float mh = 0.5f*(S00 + S11), dh = 0.5f*(S00 - S11);
    float delta = sqrtf(dh*dh + S01*S01);
    float sig1 = sqrtf(fmaxf(mh + delta, 0.0f));
    float sig2 = sqrtf(fmaxf(mh - delta, 0.0f));
    float e0, e1;
    if (dh >= 0.0f) { e0 = delta + dh; e1 = S01; }
    else            { e0 = S01;        e1 = delta - dh; }
    float elen = sqrtf(e0*e0 + e1*e1);
    float vc, vs;
    if (elen > 1e-30f) { float il = 1.0f/elen; vc = e0*il; vs = e1*il; }
    else               { vc = 1.0f; vs = 0.0f; }
    float inv1 = 1.0f / fmaxf(sig1, 1e-30f);
    float inv2 = 1.0f / fmaxf(sig2, 1e-30f);
    float u1x = ( a*vc + b*vs) * inv1, u1y = ( c*vc + d*vs) * inv1;
    float u2x = (-a*vs + b*vc) * inv2, u2y = (-c*vs + d*vc) * inv2;

    if (m == 2) {   // snow plasticity
        float c1 = fminf(fmaxf(sig1, 1.0f - 2.5e-2f), 1.0f + 4.5e-3f);
        float c2 = fminf(fmaxf(sig2, 1.0f - 2.5e-2f), 1.0f + 4.5e-3f);
        jp = jp * (sig1 / c1) * (sig2 / c2);
        sig1 = c1; sig2 = c2;
    }
    float J = sig1 * sig2;

    if (m == 0) {              // fluid: F = sqrt(J) I
        float s = sqrtf(J);
        a = s; b = 0.0f; c = 0.0f; d = s;
    } else if (m == 2) {       // snow: F = U diag(sig) Vh
        a = sig1*u1x*vc - sig2*u2x*vs;
        b = sig1*u1x*vs + sig2*u2x*vc;
        c = sig1*u1y*vc - sig2*u2y*vs;
        d = sig1*u1y*vs + sig2*u2y*vc;
    }
    float R00 = u1x*vc - u2x*vs, R01 = u1x*vs + u2x*vc;
    float R10 = u1y*vc - u2y*vs, R11 = u1y*vs + u2y*vc;

    float k2mu = 2.0f * mu;
    float fr00 = a - R00, fr01 = b - R01, fr10 = c - R10, fr11 = d - R11;
    float ljj  = lam * J * (J - 1.0f);
    float st00 = k2mu*(fr00*a + fr01*b) + ljj;
    float st01 = k2mu*(fr00*c + fr01*d);
    float st10 = k2mu*(fr10*a + fr11*b);
    float st11 = k2mu*(fr10*c + fr11*d) + ljj;
    const float coef = -DT * P_VOL * 4.0f * INV_DX * INV_DX;
    float A00 = coef*st00 + P_MASS*C00;
    float A01 = coef*st01 + P_MASS*C01;
    float A10 = coef*st10 + P_MASS*C10;
    float A11 = coef*st11 + P_MASS*C11;

    // record: {px*INV_DX, py*INV_DX, bx_, by_} {A00, A01, A10, A11}
    float bx_ = P_MASS*vp.x - (A00*px + A01*py);
    float by_ = P_MASS*vp.y - (A10*px + A11*py);

    int bidx = bin_of(px, py);
    int sidx = starts[bidx] + rank[i];
    srec0[sidx] = make_float4(px * INV_DX, py * INV_DX, bx_, by_);
    srec1[sidx] = make_float4(A00, A01, A10, A11);

    F_out4[i]  = make_float4(a, b, c, d);
    mat_out[i] = (float)m;
    Jp_out[i]  = jp;
}

__global__ __launch_bounds__(256) void compute_scatter_kernel(
    const float* __restrict__ x, const float* __restrict__ v,
    const float* __restrict__ C, const float* __restrict__ F,
    const int* __restrict__ mat, const float* __restrict__ Jp,
    const int* __restrict__ starts, const int* __restrict__ rank,
    float4* __restrict__ srec0, float4* __restrict__ srec1,
    float* __restrict__ F_out, float* __restrict__ mat_out, float* __restrict__ Jp_out,
    int n)
{
    int t = blockIdx.x * blockDim.x + threadIdx.x;
    int half = n >> 1;
    const float2* x2 = (const float2*)x;
    const float2* v2 = (const float2*)v;
    const float4* C4 = (const float4*)C;
    const float4* F4 = (const float4*)F;
    float4* F_out4 = (float4*)F_out;

    if (t < half) {
        // two independent particles per thread -> 2x memory/dep-chain ILP
        particle_update(t,        x2, v2, C4, F4, mat, Jp, starts, rank,
                        srec0, srec1, F_out4, mat_out, Jp_out);
        particle_update(t + half, x2, v2, C4, F4, mat, Jp, starts, rank,
                        srec0, srec1, F_out4, mat_out, Jp_out);
    } else if ((n & 1) && t == half) {      // odd-n tail (not hit for N=2^20)
        particle_update(n - 1, x2, v2, C4, F4, mat, Jp, starts, rank,
                        srec0, srec1, F_out4, mat_out, Jp_out);
    }
}

// 8 threads per grid cell: gather from 3 contiguous sorted ranges (strided by
// slice, 2x unrolled), shuffle-reduce within the 8-lane group, fuse grid ops.
__global__ __launch_bounds__(256) void gather_grid_kernel(
    const float4* __restrict__ srec0, const float4* __restrict__ srec1,
    const int* __restrict__ starts, float2* __restrict__ gv)
{
    int gtid  = blockIdx.x * blockDim.x + threadIdx.x;
    int cell  = gtid >> 3;
    int slice = gtid & 7;
    int gi = cell >> 8, gj = cell & (NG - 1);

    float fgi = (float)gi, fgj = (float)gj;
    float posx = fgi * DX, posy = fgj * DX;
    float msum = 0.0f, mvx = 0.0f, mvy = 0.0f;

    int i0 = max(gi - 2, 0);
    int j0 = max(gj - 2, 0);

    for (int bi = i0; bi <= gi; ++bi) {
        int row = bi << 8;
        int s = starts[row + j0];
        int e = starts[row + gj + 1];   // end of bin (bi, gj); starts[NG2]=n
        for (int k = s + slice; k < e; k += 16) {
            float4 r0 = srec0[k];
            float4 r1 = srec1[k];
            int k2 = k + 8;
            bool sec = (k2 < e);
            float4 q0, q1;
            if (sec) { q0 = srec0[k2]; q1 = srec1[k2]; }
            float w = bw(r0.x - fgi) * bw(r0.y - fgj);
            msum += w;
            mvx  += w * (r0.z + r1.x * posx + r1.y * posy);
            mvy  += w * (r0.w + r1.z * posx + r1.w * posy);
            if (sec) {
                float w2 = bw(q0.x - fgi) * bw(q0.y - fgj);
                msum += w2;
                mvx  += w2 * (q0.z + q1.x * posx + q1.y * posy);
                mvy  += w2 * (q0.w + q1.z * posx + q1.w * posy);
            }
        }
    }

    // reduce across the 8 slices (lanes differing in bits 0..2 of lane id)
    #pragma unroll
    for (int off = 1; off < 8; off <<= 1) {
        msum += __shfl_xor(msum, off);
        mvx  += __shfl_xor(mvx,  off);
        mvy  += __shfl_xor(mvy,  off);
    }

    if (slice == 0) {
        float mass = msum * P_MASS;
        float vx = mvx, vy = mvy;
        if (mass > 0.0f) {
            float im = 1.0f / fmaxf(mass, 1e-12f);
            vx *= im; vy *= im;
        }
        vy -= DT * GRAV;
        if (gi < 3)      vx = fmaxf(vx, 0.0f);
        if (gi >= NG-2)  vx = fminf(vx, 0.0f);
        if (gj < 3)      vy = fmaxf(vy, 0.0f);
        if (gj >= NG-2)  vy = fminf(vy, 0.0f);
        gv[cell] = make_float2(vx, vy);
    }
}

__global__ __launch_bounds__(256) void g2p_kernel(
    const float* __restrict__ x, const float2* __restrict__ gv,
    float* __restrict__ x_out, float* __restrict__ v_out, float* __restrict__ C_out,
    int n)
{
    int i = blockIdx.x * blockDim.x + threadIdx.x;
    if (i >= n) return;

    float2 xp = ((const float2*)x)[i];
    float px = xp.x, py = xp.y;
    float bxf = floorf(px * INV_DX - 0.5f), byf = floorf(py * INV_DX - 0.5f);
    float fx = px * INV_DX - bxf, fy = py * INV_DX - byf;
    float wxs[3] = { 0.5f*(1.5f-fx)*(1.5f-fx), 0.75f-(fx-1.0f)*(fx-1.0f), 0.5f*(fx-0.5f)*(fx-0.5f) };
    float wys[3] = { 0.5f*(1.5f-fy)*(1.5f-fy), 0.75f-(fy-1.0f)*(fy-1.0f), 0.5f*(fy-0.5f)*(fy-0.5f) };
    int bix = (int)bxf, biy = (int)byf;

    float nvx = 0.0f, nvy = 0.0f;
    float c00 = 0.0f, c01 = 0.0f, c10 = 0.0f, c11 = 0.0f;
    #pragma unroll
    for (int ii = 0; ii < 3; ++ii) {
        float posx = (bxf + (float)ii) * DX;
        int rowbase = (bix + ii) * NG + biy;
        #pragma unroll
        for (int jj = 0; jj < 3; ++jj) {
            float w = wxs[ii] * wys[jj];
            float posy = (byf + (float)jj) * DX;
            float2 g = gv[rowbase + jj];
            nvx += w * g.x; nvy += w * g.y;
            c00 += w * g.x * posx; c01 += w * g.x * posy;
            c10 += w * g.y * posx; c11 += w * g.y * posy;
        }
    }
    const float K = 4.0f * INV_DX * INV_DX;
    c00 = (c00 - nvx * px) * K; c01 = (c01 - nvx * py) * K;
    c10 = (c10 - nvy * px) * K; c11 = (c11 - nvy * py) * K;

    ((float2*)x_out)[i] = make_float2(px + DT * nvx, py + DT * nvy);
    ((float2*)v_out)[i] = make_float2(nvx, nvy);
    ((float4*)C_out)[i] = make_float4(c00, c01, c10, c11);
}

extern "C" void kernel_launch(void* const* d_in, const int* in_sizes, int n_in,
                              void* d_out, int out_size, void* d_ws, size_t ws_size,
                              hipStream_t stream) {
    const float* x   = (const float*)d_in[0];
    const float* v   = (const float*)d_in[1];
    const float* C   = (const float*)d_in[2];
    const float* F   = (const float*)d_in[3];
    const int*   mat = (const int*)d_in[4];
    const float* Jp  = (const float*)d_in[5];

    int n = in_sizes[0] / 2;

    float* out     = (float*)d_out;
    float* x_out   = out;
    float* v_out   = out + (size_t)2*n;
    float* C_out   = out + (size_t)4*n;
    float* F_out   = out + (size_t)8*n;
    float* mat_out = out + (size_t)12*n;
    float* Jp_out  = out + (size_t)13*n;

    int blocks = (n + 255) / 256;

    // workspace layout
    char* ws = (char*)d_ws;
    size_t off = 0;
    int* counts = (int*)(ws + off); off += (size_t)NG2 * 4;
    int* starts = (int*)(ws + off); off += (size_t)(NG2 + 1) * 4;
    int* bsum   = (int*)(ws + off); off += 256 * 4;
    int* rank   = (int*)(ws + off); off += (size_t)n * 4;
    off = (off + 15) & ~(size_t)15;          // 16B align for float4 records
    float4* srec0 = (float4*)(ws + off); off += (size_t)n * 16;
    float4* srec1 = (float4*)(ws + off); off += (size_t)n * 16;
    float2* gv    = (float2*)(ws + off); off += (size_t)NG2 * 8;

    hipMemsetAsync(counts, 0, (size_t)NG2 * 4, stream);
    binrank_kernel<<<blocks, 256, 0, stream>>>(x, counts, rank, n);
    scan1_kernel<<<NG2/256, 256, 0, stream>>>(counts, starts, bsum);
    scan2_kernel<<<1, 256, 0, stream>>>(bsum);
    scan3_kernel<<<NG2/256, 256, 0, stream>>>(starts, bsum, n);
    int half_blocks = ((n + 1) / 2 + 255) / 256;
    compute_scatter_kernel<<<half_blocks, 256, 0, stream>>>(x, v, C, F, mat, Jp,
                                                            starts, rank, srec0, srec1,
                                                            F_out, mat_out, Jp_out, n);
    gather_grid_kernel<<<(NG2*8)/256, 256, 0, stream>>>(srec0, srec1, starts, gv);
    g2p_kernel<<<blocks, 256, 0, stream>>>(x, gv, x_out, v_out, C_out, n);
}

// Round 5
// 146.663 us; speedup vs baseline: 10.2621x; 1.0069x over previous
//
#include <hip/hip_runtime.h>

#define NG 256
#define NG2 (NG*NG)

constexpr float DX      = 1.0f / 256.0f;
constexpr float INV_DX  = 256.0f;
constexpr float DT      = 2e-5f;
constexpr float P_VOL   = (1.0f/512.0f) * (1.0f/512.0f);
constexpr float P_MASS  = P_VOL;           // rho = 1
constexpr float MU_0    = 1000.0f / (2.0f * 1.2f);            // E/(2(1+nu))
constexpr float LAM_0   = 1000.0f * 0.2f / (1.2f * 0.6f);     // E nu/((1+nu)(1-2nu))
constexpr float GRAV    = 50.0f;

__device__ __forceinline__ int bin_of(float px, float py) {
    int bx = (int)floorf(px * INV_DX - 0.5f);
    int by = (int)floorf(py * INV_DX - 0.5f);
    bx = min(max(bx, 0), NG - 1);
    by = min(max(by, 0), NG - 1);
    return (bx << 8) | by;
}

// quadratic B-spline weight as a function of (node - particle) distance in cells
__device__ __forceinline__ float bw(float t) {
    float at = fabsf(t);
    float a  = fmaxf(1.5f - at, 0.0f);
    float w1 = 0.75f - t * t;
    float w2 = 0.5f * a * a;
    return (at < 0.5f) ? w1 : w2;
}

// ---------------- binning + scan ----------------

__global__ __launch_bounds__(256) void binrank_kernel(
    const float* __restrict__ x, int* __restrict__ counts, int* __restrict__ rank, int n)
{
    int i = blockIdx.x * blockDim.x + threadIdx.x;
    if (i >= n) return;
    float2 p = ((const float2*)x)[i];
    int b = bin_of(p.x, p.y);
    rank[i] = atomicAdd(&counts[b], 1);
}

__global__ __launch_bounds__(256) void scan1_kernel(
    const int* __restrict__ counts, int* __restrict__ starts, int* __restrict__ bsum)
{
    __shared__ int tmp[256];
    int t = threadIdx.x, b = blockIdx.x;
    int v = counts[b * 256 + t];
    tmp[t] = v;
    __syncthreads();
    #pragma unroll
    for (int off = 1; off < 256; off <<= 1) {
        int add = (t >= off) ? tmp[t - off] : 0;
        __syncthreads();
        tmp[t] += add;
        __syncthreads();
    }
    starts[b * 256 + t] = tmp[t] - v;          // exclusive within block
    if (t == 255) bsum[b] = tmp[255];          // block total
}

__global__ __launch_bounds__(256) void scan2_kernel(int* __restrict__ bsum)
{
    __shared__ int tmp[256];
    int t = threadIdx.x;
    int v = bsum[t];
    tmp[t] = v;
    __syncthreads();
    #pragma unroll
    for (int off = 1; off < 256; off <<= 1) {
        int add = (t >= off) ? tmp[t - off] : 0;
        __syncthreads();
        tmp[t] += add;
        __syncthreads();
    }
    bsum[t] = tmp[t] - v;                      // exclusive
}

__global__ __launch_bounds__(256) void scan3_kernel(
    int* __restrict__ starts, const int* __restrict__ bsum, int n)
{
    int i = blockIdx.x * blockDim.x + threadIdx.x;
    if (i < NG2) starts[i] += bsum[i >> 8];
    if (i == 0) starts[NG2] = n;
}

// ---------------- particle update + sorted record scatter ----------------

struct PIn {
    float2 xp, vp;
    float4 Cp, Fp;
    int    m;
    float  jp;
    int    sidx;
};

__device__ __forceinline__ PIn load_particle(
    int i,
    const float2* __restrict__ x2, const float2* __restrict__ v2,
    const float4* __restrict__ C4, const float4* __restrict__ F4,
    const int* __restrict__ mat, const float* __restrict__ Jp,
    const int* __restrict__ starts, const int* __restrict__ rank)
{
    PIn p;
    p.xp = x2[i];
    p.vp = v2[i];
    p.Cp = C4[i];
    p.Fp = F4[i];
    p.m  = mat[i];
    p.jp = Jp[i];
    int r = rank[i];
    p.sidx = starts[bin_of(p.xp.x, p.xp.y)] + r;
    return p;
}

__device__ __forceinline__ void compute_store_particle(
    const PIn& p, int i,
    float4* __restrict__ srec0, float4* __restrict__ srec1,
    float4* __restrict__ F_out4, float* __restrict__ mat_out, float* __restrict__ Jp_out)
{
    float px = p.xp.x, py = p.xp.y;
    float C00 = p.Cp.x, C01 = p.Cp.y, C10 = p.Cp.z, C11 = p.Cp.w;
    float a = p.Fp.x, b = p.Fp.y, c = p.Fp.z, d = p.Fp.w;
    int   m = p.m;
    float jp = p.jp;

    // F += dt * C @ F
    float na = a + DT*(C00*a + C01*c);
    float nb = b + DT*(C00*b + C01*d);
    float nc = c + DT*(C10*a + C11*c);
    float nd = d + DT*(C10*b + C11*d);
    a = na; b = nb; c = nc; d = nd;

    float h = expf(10.0f * (1.0f - jp));
    if (m == 1) h = 0.3f;
    float mu  = (m == 0) ? 0.0f : MU_0 * h;
    float lam = LAM_0 * h;

    // closed-form 2x2 SVD via eigendecomposition of A^T A
    float S00 = a*a + c*c, S01 = a*b + c*d, S11 = b*b + d*d;
    float mh = 0.5f*(S00 + S11), dh = 0.5f*(S00 - S11);
    float delta = sqrtf(dh*dh + S01*S01);
    float sig1 = sqrtf(fmaxf(mh + delta, 0.0f));
    float sig2 = sqrtf(fmaxf(mh - delta, 0.0f));
    float e0, e1;
    if (dh >= 0.0f) { e0 = delta + dh; e1 = S01; }
    else            { e0 = S01;        e1 = delta - dh; }
    float elen = sqrtf(e0*e0 + e1*e1);
    float vc, vs;
    if (elen > 1e-30f) { float il = 1.0f/elen; vc = e0*il; vs = e1*il; }
    else               { vc = 1.0f; vs = 0.0f; }
    float inv1 = 1.0f / fmaxf(sig1, 1e-30f);
    float inv2 = 1.0f / fmaxf(sig2, 1e-30f);
    float u1x = ( a*vc + b*vs) * inv1, u1y = ( c*vc + d*vs) * inv1;
    float u2x = (-a*vs + b*vc) * inv2, u2y = (-c*vs + d*vc) * inv2;

    if (m == 2) {   // snow plasticity
        float c1 = fminf(fmaxf(sig1, 1.0f - 2.5e-2f), 1.0f + 4.5e-3f);
        float c2 = fminf(fmaxf(sig2, 1.0f - 2.5e-2f), 1.0f + 4.5e-3f);
        jp = jp * (sig1 / c1) * (sig2 / c2);
        sig1 = c1; sig2 = c2;
    }
    float J = sig1 * sig2;

    if (m == 0) {              // fluid: F = sqrt(J) I
        float s = sqrtf(J);
        a = s; b = 0.0f; c = 0.0f; d = s;
    } else if (m == 2) {       // snow: F = U diag(sig) Vh
        a = sig1*u1x*vc - sig2*u2x*vs;
        b = sig1*u1x*vs + sig2*u2x*vc;
        c = sig1*u1y*vc - sig2*u2y*vs;
        d = sig1*u1y*vs + sig2*u2y*vc;
    }
    float R00 = u1x*vc - u2x*vs, R01 = u1x*vs + u2x*vc;
    float R10 = u1y*vc - u2y*vs, R11 = u1y*vs + u2y*vc;

    float k2mu = 2.0f * mu;
    float fr00 = a - R00, fr01 = b - R01, fr10 = c - R10, fr11 = d - R11;
    float ljj  = lam * J * (J - 1.0f);
    float st00 = k2mu*(fr00*a + fr01*b) + ljj;
    float st01 = k2mu*(fr00*c + fr01*d);
    float st10 = k2mu*(fr10*a + fr11*b);
    float st11 = k2mu*(fr10*c + fr11*d) + ljj;
    const float coef = -DT * P_VOL * 4.0f * INV_DX * INV_DX;
    float A00 = coef*st00 + P_MASS*C00;
    float A01 = coef*st01 + P_MASS*C01;
    float A10 = coef*st10 + P_MASS*C10;
    float A11 = coef*st11 + P_MASS*C11;

    float bx_ = P_MASS*p.vp.x - (A00*px + A01*py);
    float by_ = P_MASS*p.vp.y - (A10*px + A11*py);

    srec0[p.sidx] = make_float4(px * INV_DX, py * INV_DX, bx_, by_);
    srec1[p.sidx] = make_float4(A00, A01, A10, A11);

    F_out4[i]  = make_float4(a, b, c, d);
    mat_out[i] = (float)m;
    Jp_out[i]  = jp;
}

__global__ __launch_bounds__(256, 4) void compute_scatter_kernel(
    const float* __restrict__ x, const float* __restrict__ v,
    const float* __restrict__ C, const float* __restrict__ F,
    const int* __restrict__ mat, const float* __restrict__ Jp,
    const int* __restrict__ starts, const int* __restrict__ rank,
    float4* __restrict__ srec0, float4* __restrict__ srec1,
    float* __restrict__ F_out, float* __restrict__ mat_out, float* __restrict__ Jp_out,
    int n)
{
    int t = blockIdx.x * blockDim.x + threadIdx.x;
    int half = n >> 1;
    const float2* x2 = (const float2*)x;
    const float2* v2 = (const float2*)v;
    const float4* C4 = (const float4*)C;
    const float4* F4 = (const float4*)F;
    float4* F_out4 = (float4*)F_out;

    if (t < half) {
        // explicit load phase: both particles' loads issue before either chain
        PIn p0 = load_particle(t,        x2, v2, C4, F4, mat, Jp, starts, rank);
        PIn p1 = load_particle(t + half, x2, v2, C4, F4, mat, Jp, starts, rank);
        // two independent compute chains; compiler free to interleave
        compute_store_particle(p0, t,        srec0, srec1, (float4*)F_out, mat_out, Jp_out);
        compute_store_particle(p1, t + half, srec0, srec1, (float4*)F_out, mat_out, Jp_out);
    } else if ((n & 1) && t == half) {      // odd-n tail (not hit for N=2^20)
        PIn p = load_particle(n - 1, x2, v2, C4, F4, mat, Jp, starts, rank);
        compute_store_particle(p, n - 1, srec0, srec1, (float4*)F_out, mat_out, Jp_out);
    }
    (void)F_out4;
}

// 8 threads per grid cell: gather from 3 contiguous sorted ranges (strided by
// slice, 2x unrolled), shuffle-reduce within the 8-lane group, fuse grid ops.
// Block index is XCD-swizzled so each XCD owns a contiguous band of grid rows
// (bin-row records then stay resident in that XCD's private L2).
__global__ __launch_bounds__(256) void gather_grid_kernel(
    const float4* __restrict__ srec0, const float4* __restrict__ srec1,
    const int* __restrict__ starts, float2* __restrict__ gv)
{
    // bijective XCD swizzle: nwg = NG2*8/256 = 2048, 2048 % 8 == 0
    int bid  = blockIdx.x;
    int swz  = (bid & 7) * (2048 / 8) + (bid >> 3);
    int gtid  = swz * 256 + threadIdx.x;
    int cell  = gtid >> 3;
    int slice = gtid & 7;
    int gi = cell >> 8, gj = cell & (NG - 1);

    float fgi = (float)gi, fgj = (float)gj;
    float posx = fgi * DX, posy = fgj * DX;
    float msum = 0.0f, mvx = 0.0f, mvy = 0.0f;

    int j0 = max(gj - 2, 0);

    // prefetch all 6 range bounds (up to 3 bin rows)
    int sArr[3], eArr[3];
    #pragma unroll
    for (int t3 = 0; t3 < 3; ++t3) {
        int bi = gi - 2 + t3;
        bool valid = (bi >= 0);
        int row = (valid ? bi : 0) << 8;
        sArr[t3] = valid ? starts[row + j0] : 0;
        eArr[t3] = valid ? starts[row + gj + 1] : 0;
    }

    #pragma unroll
    for (int t3 = 0; t3 < 3; ++t3) {
        int s = sArr[t3], e = eArr[t3];
        for (int k = s + slice; k < e; k += 16) {
            float4 r0 = srec0[k];
            float4 r1 = srec1[k];
            int k2 = k + 8;
            bool sec = (k2 < e);
            float4 q0, q1;
            if (sec) { q0 = srec0[k2]; q1 = srec1[k2]; }
            float w = bw(r0.x - fgi) * bw(r0.y - fgj);
            msum += w;
            mvx  += w * (r0.z + r1.x * posx + r1.y * posy);
            mvy  += w * (r0.w + r1.z * posx + r1.w * posy);
            if (sec) {
                float w2 = bw(q0.x - fgi) * bw(q0.y - fgj);
                msum += w2;
                mvx  += w2 * (q0.z + q1.x * posx + q1.y * posy);
                mvy  += w2 * (q0.w + q1.z * posx + q1.w * posy);
            }
        }
    }

    // reduce across the 8 slices (lanes differing in bits 0..2 of lane id)
    #pragma unroll
    for (int off = 1; off < 8; off <<= 1) {
        msum += __shfl_xor(msum, off);
        mvx  += __shfl_xor(mvx,  off);
        mvy  += __shfl_xor(mvy,  off);
    }

    if (slice == 0) {
        float mass = msum * P_MASS;
        float vx = mvx, vy = mvy;
        if (mass > 0.0f) {
            float im = 1.0f / fmaxf(mass, 1e-12f);
            vx *= im; vy *= im;
        }
        vy -= DT * GRAV;
        if (gi < 3)      vx = fmaxf(vx, 0.0f);
        if (gi >= NG-2)  vx = fminf(vx, 0.0f);
        if (gj < 3)      vy = fmaxf(vy, 0.0f);
        if (gj >= NG-2)  vy = fminf(vy, 0.0f);
        gv[cell] = make_float2(vx, vy);
    }
}

__global__ __launch_bounds__(256) void g2p_kernel(
    const float* __restrict__ x, const float2* __restrict__ gv,
    float* __restrict__ x_out, float* __restrict__ v_out, float* __restrict__ C_out,
    int n)
{
    int i = blockIdx.x * blockDim.x + threadIdx.x;
    if (i >= n) return;

    float2 xp = ((const float2*)x)[i];
    float px = xp.x, py = xp.y;
    float bxf = floorf(px * INV_DX - 0.5f), byf = floorf(py * INV_DX - 0.5f);
    float fx = px * INV_DX - bxf, fy = py * INV_DX - byf;
    float wxs[3] = { 0.5f*(1.5f-fx)*(1.5f-fx), 0.75f-(fx-1.0f)*(fx-1.0f), 0.5f*(fx-0.5f)*(fx-0.5f) };
    float wys[3] = { 0.5f*(1.5f-fy)*(1.5f-fy), 0.75f-(fy-1.0f)*(fy-1.0f), 0.5f*(fy-0.5f)*(fy-0.5f) };
    int bix = (int)bxf, biy = (int)byf;

    float nvx = 0.0f, nvy = 0.0f;
    float c00 = 0.0f, c01 = 0.0f, c10 = 0.0f, c11 = 0.0f;
    #pragma unroll
    for (int ii = 0; ii < 3; ++ii) {
        float posx = (bxf + (float)ii) * DX;
        int rowbase = (bix + ii) * NG + biy;
        #pragma unroll
        for (int jj = 0; jj < 3; ++jj) {
            float w = wxs[ii] * wys[jj];
            float posy = (byf + (float)jj) * DX;
            float2 g = gv[rowbase + jj];
            nvx += w * g.x; nvy += w * g.y;
            c00 += w * g.x * posx; c01 += w * g.x * posy;
            c10 += w * g.y * posx; c11 += w * g.y * posy;
        }
    }
    const float K = 4.0f * INV_DX * INV_DX;
    c00 = (c00 - nvx * px) * K; c01 = (c01 - nvx * py) * K;
    c10 = (c10 - nvy * px) * K; c11 = (c11 - nvy * py) * K;

    ((float2*)x_out)[i] = make_float2(px + DT * nvx, py + DT * nvy);
    ((float2*)v_out)[i] = make_float2(nvx, nvy);
    ((float4*)C_out)[i] = make_float4(c00, c01, c10, c11);
}

extern "C" void kernel_launch(void* const* d_in, const int* in_sizes, int n_in,
                              void* d_out, int out_size, void* d_ws, size_t ws_size,
                              hipStream_t stream) {
    const float* x   = (const float*)d_in[0];
    const float* v   = (const float*)d_in[1];
    const float* C   = (const float*)d_in[2];
    const float* F   = (const float*)d_in[3];
    const int*   mat = (const int*)d_in[4];
    const float* Jp  = (const float*)d_in[5];

    int n = in_sizes[0] / 2;

    float* out     = (float*)d_out;
    float* x_out   = out;
    float* v_out   = out + (size_t)2*n;
    float* C_out   = out + (size_t)4*n;
    float* F_out   = out + (size_t)8*n;
    float* mat_out = out + (size_t)12*n;
    float* Jp_out  = out + (size_t)13*n;

    int blocks = (n + 255) / 256;

    // workspace layout
    char* ws = (char*)d_ws;
    size_t off = 0;
    int* counts = (int*)(ws + off); off += (size_t)NG2 * 4;
    int* starts = (int*)(ws + off); off += (size_t)(NG2 + 1) * 4;
    int* bsum   = (int*)(ws + off); off += 256 * 4;
    int* rank   = (int*)(ws + off); off += (size_t)n * 4;
    off = (off + 15) & ~(size_t)15;          // 16B align for float4 records
    float4* srec0 = (float4*)(ws + off); off += (size_t)n * 16;
    float4* srec1 = (float4*)(ws + off); off += (size_t)n * 16;
    float2* gv    = (float2*)(ws + off); off += (size_t)NG2 * 8;

    hipMemsetAsync(counts, 0, (size_t)NG2 * 4, stream);
    binrank_kernel<<<blocks, 256, 0, stream>>>(x, counts, rank, n);
    scan1_kernel<<<NG2/256, 256, 0, stream>>>(counts, starts, bsum);
    scan2_kernel<<<1, 256, 0, stream>>>(bsum);
    scan3_kernel<<<NG2/256, 256, 0, stream>>>(starts, bsum, n);
    int half_blocks = ((n + 1) / 2 + 255) / 256;
    compute_scatter_kernel<<<half_blocks, 256, 0, stream>>>(x, v, C, F, mat, Jp,
                                                            starts, rank, srec0, srec1,
                                                            F_out, mat_out, Jp_out, n);
    gather_grid_kernel<<<(NG2*8)/256, 256, 0, stream>>>(srec0, srec1, starts, gv);
    g2p_kernel<<<blocks, 256, 0, stream>>>(x, gv, x_out, v_out, C_out, n);
}